// Round 1
// baseline (1803.508 us; speedup 1.0000x reference)
//
#include <hip/hip_runtime.h>
#include <stdint.h>

// Problem constants
#define NROWS 131072   // 32768*2048/512 rows of the block-reshaped X
#define NCOLS 512      // BLOCK
#define MROWS 32768    // N
#define DDIM  2048     // D_IN = D_OUT
#define EPSV  1e-5f

typedef __attribute__((ext_vector_type(8))) short bf16x8;
typedef __attribute__((ext_vector_type(4))) float f32x4;

__device__ __forceinline__ short f2bf(float f) {
  uint32_t u = __float_as_uint(f);
  u += 0x7fffu + ((u >> 16) & 1u);   // RNE
  return (short)(u >> 16);
}
__device__ __forceinline__ float bf2f(short s) {
  return __uint_as_float(((uint32_t)(uint16_t)s) << 16);
}

// ---------------------------------------------------------------------------
// 1) column sums of X = x.reshape(131072, 512)
// ---------------------------------------------------------------------------
__global__ __launch_bounds__(512) void colsum_kernel(const float* __restrict__ x,
                                                     float* __restrict__ colsum) {
  const int t = threadIdx.x;
  const size_t r0 = (size_t)blockIdx.x * 256;
  float s[8] = {0.f,0.f,0.f,0.f,0.f,0.f,0.f,0.f};
  for (int r = 0; r < 256; r += 8) {
#pragma unroll
    for (int u = 0; u < 8; ++u) s[u] += x[(r0 + r + u) * NCOLS + t];
  }
  float tot = ((s[0]+s[1])+(s[2]+s[3])) + ((s[4]+s[5])+(s[6]+s[7]));
  atomicAdd(&colsum[t], tot);
}

// ---------------------------------------------------------------------------
// 2) S = X^T X  (bf16 MFMA, fp32 accum), symmetric: only 128x128 tiles I<=J
//    grid (10, 64): 10 tile pairs x 64 K-chunks of 2048 rows
// ---------------------------------------------------------------------------
__global__ __launch_bounds__(256) void syrk_kernel(const float* __restrict__ x,
                                                   float* __restrict__ S) {
  const int TI[10] = {0,0,0,0,1,1,1,2,2,3};
  const int TJ[10] = {0,1,2,3,1,2,3,2,3,3};
  const int I = TI[blockIdx.x], J = TJ[blockIdx.x];
  const int baseA = I * 128, baseB = J * 128;
  const size_t k0 = (size_t)blockIdx.y * 2048;

  __shared__ short As[128][40];   // As[c][kk] = bf16(X[k0+ks+kk][baseA+c])
  __shared__ short Bs[128][40];

  const int tid = threadIdx.x;
  const int lane = tid & 63, wave = tid >> 6;
  const int wm = wave >> 1, wn = wave & 1;
  const int quad = lane >> 4, l16 = lane & 15;

  f32x4 acc[4][4];
#pragma unroll
  for (int a = 0; a < 4; ++a)
#pragma unroll
    for (int b = 0; b < 4; ++b)
#pragma unroll
      for (int r = 0; r < 4; ++r) acc[a][b][r] = 0.f;

  for (int ks = 0; ks < 2048; ks += 32) {
#pragma unroll
    for (int i = 0; i < 4; ++i) {
      int idx = tid + i * 256;          // 1024 float4 slots
      int kk = idx >> 5, c4 = idx & 31;
      size_t row = k0 + ks + kk;
      float4 va = *(const float4*)&x[row * NCOLS + baseA + c4 * 4];
      As[c4*4+0][kk] = f2bf(va.x);
      As[c4*4+1][kk] = f2bf(va.y);
      As[c4*4+2][kk] = f2bf(va.z);
      As[c4*4+3][kk] = f2bf(va.w);
      float4 vb = *(const float4*)&x[row * NCOLS + baseB + c4 * 4];
      Bs[c4*4+0][kk] = f2bf(vb.x);
      Bs[c4*4+1][kk] = f2bf(vb.y);
      Bs[c4*4+2][kk] = f2bf(vb.z);
      Bs[c4*4+3][kk] = f2bf(vb.w);
    }
    __syncthreads();
    bf16x8 af[4], bfr[4];
#pragma unroll
    for (int tm = 0; tm < 4; ++tm)
      af[tm] = *(const bf16x8*)&As[wm*64 + tm*16 + l16][quad * 8];
#pragma unroll
    for (int tn = 0; tn < 4; ++tn)
      bfr[tn] = *(const bf16x8*)&Bs[wn*64 + tn*16 + l16][quad * 8];
#pragma unroll
    for (int tm = 0; tm < 4; ++tm)
#pragma unroll
      for (int tn = 0; tn < 4; ++tn)
        acc[tm][tn] = __builtin_amdgcn_mfma_f32_16x16x32_bf16(af[tm], bfr[tn], acc[tm][tn], 0, 0, 0);
    __syncthreads();
  }
#pragma unroll
  for (int tm = 0; tm < 4; ++tm)
#pragma unroll
    for (int tn = 0; tn < 4; ++tn)
#pragma unroll
      for (int r = 0; r < 4; ++r) {
        int i = baseA + wm*64 + tm*16 + quad*4 + r;
        int j = baseB + wn*64 + tn*16 + l16;
        atomicAdd(&S[i * NCOLS + j], acc[tm][tn][r]);
      }
}

// ---------------------------------------------------------------------------
// 3) mean, cov finalize (+ Frobenius norm^2), Y/Z init
// ---------------------------------------------------------------------------
__global__ void mean_kernel(const float* __restrict__ colsum, float* __restrict__ mean) {
  int i = blockIdx.x * 256 + threadIdx.x;
  if (i < NCOLS) mean[i] = colsum[i] * (1.0f / (float)NROWS);
}

__global__ __launch_bounds__(256) void finalize_cov_kernel(const float* __restrict__ S,
                                                           const float* __restrict__ mean,
                                                           float* __restrict__ cov,
                                                           float* __restrict__ norm2) {
  const int i = blockIdx.x;
  const float mi = mean[i];
  float local = 0.f;
  for (int j = threadIdx.x; j < NCOLS; j += 256) {
    float s = ((i >> 7) > (j >> 7)) ? S[j * NCOLS + i] : S[i * NCOLS + j];
    float c = s * (1.0f / (float)NROWS) - mi * mean[j];
    if (i == j) c += EPSV;
    cov[i * NCOLS + j] = c;
    local += c * c;
  }
  __shared__ float red[256];
  red[threadIdx.x] = local;
  __syncthreads();
  for (int s = 128; s > 0; s >>= 1) {
    if (threadIdx.x < s) red[threadIdx.x] += red[threadIdx.x + s];
    __syncthreads();
  }
  if (threadIdx.x == 0) atomicAdd(norm2, red[0]);
}

__global__ void init_yz_kernel(const float* __restrict__ cov, const float* __restrict__ norm2,
                               float* __restrict__ Y, float* __restrict__ Z) {
  int idx = blockIdx.x * 256 + threadIdx.x;   // 262144 elements
  float rn = rsqrtf(*norm2);                  // 1/normA = norm2^{-1/2}
  Y[idx] = cov[idx] * rn;
  int i = idx >> 9, j = idx & 511;
  Z[idx] = (i == j) ? 1.f : 0.f;
}

// ---------------------------------------------------------------------------
// 4) fp32 512x512 GEMMs for Denman-Beavers
// ---------------------------------------------------------------------------
template <int MODE>   // 0: C = A@B   1: C = 1.5I - 0.5*(A@B)
__device__ __forceinline__ void gemm512_body(const float* __restrict__ A,
                                             const float* __restrict__ B,
                                             float* __restrict__ C,
                                             int m0, int n0) {
  __shared__ float As[16][65];   // As[kk][m]
  __shared__ float Bs[16][64];   // Bs[kk][n]
  const int tid = threadIdx.x;
  const int ty = tid >> 4, tx = tid & 15;
  float acc[4][4] = {};
  for (int k = 0; k < 512; k += 16) {
    {
      int row = tid >> 2, q = tid & 3;
      float4 va = *(const float4*)&A[(size_t)(m0 + row) * 512 + k + q * 4];
      As[q*4+0][row] = va.x; As[q*4+1][row] = va.y;
      As[q*4+2][row] = va.z; As[q*4+3][row] = va.w;
      int kk = tid >> 4, qb = tid & 15;
      float4 vb = *(const float4*)&B[(size_t)(k + kk) * 512 + n0 + qb * 4];
      *(float4*)&Bs[kk][qb * 4] = vb;
    }
    __syncthreads();
#pragma unroll
    for (int kk = 0; kk < 16; ++kk) {
      float a[4], b[4];
#pragma unroll
      for (int i = 0; i < 4; ++i) a[i] = As[kk][ty + 16*i];
#pragma unroll
      for (int j = 0; j < 4; ++j) b[j] = Bs[kk][tx + 16*j];
#pragma unroll
      for (int i = 0; i < 4; ++i)
#pragma unroll
        for (int j = 0; j < 4; ++j) acc[i][j] = fmaf(a[i], b[j], acc[i][j]);
    }
    __syncthreads();
  }
#pragma unroll
  for (int i = 0; i < 4; ++i)
#pragma unroll
    for (int j = 0; j < 4; ++j) {
      int r = m0 + ty + 16*i, c = n0 + tx + 16*j;
      float v = MODE ? ((r == c ? 1.5f : 0.f) - 0.5f * acc[i][j]) : acc[i][j];
      C[(size_t)r * 512 + c] = v;
    }
}

__global__ __launch_bounds__(256) void gemm512_T_kernel(const float* __restrict__ Z,
                                                        const float* __restrict__ Y,
                                                        float* __restrict__ T) {
  gemm512_body<1>(Z, Y, T, blockIdx.y * 64, blockIdx.x * 64);
}

__global__ __launch_bounds__(256) void gemm512_pair_kernel(const float* __restrict__ A0, const float* __restrict__ B0, float* __restrict__ C0,
                                                           const float* __restrict__ A1, const float* __restrict__ B1, float* __restrict__ C1) {
  const float* A = blockIdx.z ? A1 : A0;
  const float* B = blockIdx.z ? B1 : B0;
  float* C = blockIdx.z ? C1 : C0;
  gemm512_body<0>(A, B, C, blockIdx.y * 64, blockIdx.x * 64);
}

// ---------------------------------------------------------------------------
// 5) w = weight.reshape(8192,512) @ (Z * normA^{-1/2}), output bf16
// ---------------------------------------------------------------------------
__global__ __launch_bounds__(256) void wgemm_kernel(const float* __restrict__ Wt,
                                                    const float* __restrict__ Zf,
                                                    const float* __restrict__ norm2,
                                                    short* __restrict__ wbf) {
  __shared__ float As[16][65];
  __shared__ float Bs[16][64];
  const int m0 = blockIdx.y * 64, n0 = blockIdx.x * 64;
  const int tid = threadIdx.x;
  const int ty = tid >> 4, tx = tid & 15;
  const float s = rsqrtf(sqrtf(*norm2));   // normA^{-1/2} = norm2^{-1/4}
  float acc[4][4] = {};
  for (int k = 0; k < 512; k += 16) {
    {
      int row = tid >> 2, q = tid & 3;
      float4 va = *(const float4*)&Wt[(size_t)(m0 + row) * 512 + k + q * 4];
      As[q*4+0][row] = va.x; As[q*4+1][row] = va.y;
      As[q*4+2][row] = va.z; As[q*4+3][row] = va.w;
      int kk = tid >> 4, qb = tid & 15;
      float4 vb = *(const float4*)&Zf[(size_t)(k + kk) * 512 + n0 + qb * 4];
      *(float4*)&Bs[kk][qb * 4] = vb;
    }
    __syncthreads();
#pragma unroll
    for (int kk = 0; kk < 16; ++kk) {
      float a[4], b[4];
#pragma unroll
      for (int i = 0; i < 4; ++i) a[i] = As[kk][ty + 16*i];
#pragma unroll
      for (int j = 0; j < 4; ++j) b[j] = Bs[kk][tx + 16*j];
#pragma unroll
      for (int i = 0; i < 4; ++i)
#pragma unroll
        for (int j = 0; j < 4; ++j) acc[i][j] = fmaf(a[i], b[j], acc[i][j]);
    }
    __syncthreads();
  }
#pragma unroll
  for (int i = 0; i < 4; ++i)
#pragma unroll
    for (int j = 0; j < 4; ++j) {
      int r = m0 + ty + 16*i, c = n0 + tx + 16*j;
      wbf[(size_t)r * 512 + c] = f2bf(acc[i][j] * s);
    }
}

// ---------------------------------------------------------------------------
// 6) b[o] = bias[o] - sum_k wfull[o][k] * mean[k % 512]
// ---------------------------------------------------------------------------
__global__ __launch_bounds__(256) void bvec_kernel(const short* __restrict__ wbf,
                                                   const float* __restrict__ mean,
                                                   const float* __restrict__ bias,
                                                   float* __restrict__ bvec) {
  const int o = blockIdx.x;
  float p = 0.f;
  for (int k = threadIdx.x; k < DDIM; k += 256)
    p += bf2f(wbf[(size_t)o * DDIM + k]) * mean[k & 511];
  __shared__ float red[256];
  red[threadIdx.x] = p;
  __syncthreads();
  for (int s = 128; s > 0; s >>= 1) {
    if (threadIdx.x < s) red[threadIdx.x] += red[threadIdx.x + s];
    __syncthreads();
  }
  if (threadIdx.x == 0) bvec[o] = bias[o] - red[0];
}

// ---------------------------------------------------------------------------
// 7) out = x @ w^T + b   (bf16 MFMA, fp32 accum/output)
//    x [32768][2048] fp32 (converted in staging), w [2048][2048] bf16
//    grid (16, 256): blockIdx.x = n-tile (fast, shares x panel in L2)
// ---------------------------------------------------------------------------
__global__ __launch_bounds__(256) void final_gemm_kernel(const float* __restrict__ x,
                                                         const short* __restrict__ wbf,
                                                         const float* __restrict__ bvec,
                                                         float* __restrict__ out) {
  __shared__ short Xs[128][40];   // Xs[m][kk]
  __shared__ short Ws[128][40];   // Ws[n][kk]
  const int n0 = blockIdx.x * 128, m0 = blockIdx.y * 128;
  const int tid = threadIdx.x;
  const int lane = tid & 63, wave = tid >> 6;
  const int wm = wave >> 1, wn = wave & 1;
  const int quad = lane >> 4, l16 = lane & 15;

  f32x4 acc[4][4];
#pragma unroll
  for (int a = 0; a < 4; ++a)
#pragma unroll
    for (int b = 0; b < 4; ++b)
#pragma unroll
      for (int r = 0; r < 4; ++r) acc[a][b][r] = 0.f;

  for (int kt = 0; kt < DDIM; kt += 32) {
    // stage x (fp32 -> bf16)
#pragma unroll
    for (int i = 0; i < 4; ++i) {
      int idx = tid + i * 256;            // 1024 float4
      int row = idx >> 3, c4 = idx & 7;
      float4 v = *(const float4*)&x[(size_t)(m0 + row) * DDIM + kt + c4 * 4];
      uint32_t p0 = (uint32_t)(uint16_t)f2bf(v.x) | ((uint32_t)(uint16_t)f2bf(v.y) << 16);
      uint32_t p1 = (uint32_t)(uint16_t)f2bf(v.z) | ((uint32_t)(uint16_t)f2bf(v.w) << 16);
      *(uint2*)&Xs[row][c4 * 4] = make_uint2(p0, p1);
    }
    // stage w (already bf16)
#pragma unroll
    for (int i = 0; i < 2; ++i) {
      int idx = tid + i * 256;            // 512 x 16B
      int row = idx >> 2, c8 = idx & 3;
      int4 v = *(const int4*)&wbf[(size_t)(n0 + row) * DDIM + kt + c8 * 8];
      *(int4*)&Ws[row][c8 * 8] = v;
    }
    __syncthreads();
    bf16x8 af[4], bfr[4];
#pragma unroll
    for (int tm = 0; tm < 4; ++tm)
      af[tm] = *(const bf16x8*)&Xs[wm*64 + tm*16 + l16][quad * 8];
#pragma unroll
    for (int tn = 0; tn < 4; ++tn)
      bfr[tn] = *(const bf16x8*)&Ws[wn*64 + tn*16 + l16][quad * 8];
#pragma unroll
    for (int tm = 0; tm < 4; ++tm)
#pragma unroll
      for (int tn = 0; tn < 4; ++tn)
        acc[tm][tn] = __builtin_amdgcn_mfma_f32_16x16x32_bf16(af[tm], bfr[tn], acc[tm][tn], 0, 0, 0);
    __syncthreads();
  }
  float bv[4];
#pragma unroll
  for (int tn = 0; tn < 4; ++tn) bv[tn] = bvec[n0 + wn*64 + tn*16 + l16];
#pragma unroll
  for (int tm = 0; tm < 4; ++tm)
#pragma unroll
    for (int tn = 0; tn < 4; ++tn)
#pragma unroll
      for (int r = 0; r < 4; ++r) {
        size_t row = (size_t)(m0 + wm*64 + tm*16 + quad*4 + r);
        int col = n0 + wn*64 + tn*16 + l16;
        out[row * DDIM + col] = acc[tm][tn][r] + bv[tn];
      }
}

// ---------------------------------------------------------------------------
extern "C" void kernel_launch(void* const* d_in, const int* in_sizes, int n_in,
                              void* d_out, int out_size, void* d_ws, size_t ws_size,
                              hipStream_t stream) {
  const float* x      = (const float*)d_in[0];   // 32768*2048
  const float* weight = (const float*)d_in[1];   // 2048*2048
  const float* bias   = (const float*)d_in[2];   // 2048
  float* out = (float*)d_out;
  char* ws = (char*)d_ws;

  float* colsum = (float*)(ws + 0);          // 2 KB
  float* mean   = (float*)(ws + 4096);       // 2 KB
  float* norm2  = (float*)(ws + 8192);       // 4 B
  float* bvec   = (float*)(ws + 12288);      // 8 KB
  float* Sbuf   = (float*)(ws + (1u << 20)); // 1 MB
  float* covb   = (float*)(ws + (2u << 20));
  float* Ybuf   = (float*)(ws + (3u << 20));
  float* Zbuf   = (float*)(ws + (4u << 20));
  float* Tbuf   = (float*)(ws + (5u << 20));
  float* Y2buf  = (float*)(ws + (6u << 20));
  float* Z2buf  = (float*)(ws + (7u << 20));
  short* wbf    = (short*)(ws + (8u << 20)); // 8 MB -> 16 MB total

  hipMemsetAsync(colsum, 0, 512 * 4, stream);
  hipMemsetAsync(norm2, 0, 4, stream);
  hipMemsetAsync(Sbuf, 0, 512 * 512 * 4, stream);

  colsum_kernel<<<512, 512, 0, stream>>>(x, colsum);
  syrk_kernel<<<dim3(10, 64), 256, 0, stream>>>(x, Sbuf);
  mean_kernel<<<2, 256, 0, stream>>>(colsum, mean);
  finalize_cov_kernel<<<512, 256, 0, stream>>>(Sbuf, mean, covb, norm2);
  init_yz_kernel<<<1024, 256, 0, stream>>>(covb, norm2, Ybuf, Zbuf);

  float* Y = Ybuf; float* Z = Zbuf; float* Y2 = Y2buf; float* Z2 = Z2buf;
  for (int it = 0; it < 5; ++it) {
    gemm512_T_kernel<<<dim3(8, 8), 256, 0, stream>>>(Z, Y, Tbuf);
    gemm512_pair_kernel<<<dim3(8, 8, 2), 256, 0, stream>>>(Y, Tbuf, Y2, Tbuf, Z, Z2);
    float* t;
    t = Y; Y = Y2; Y2 = t;
    t = Z; Z = Z2; Z2 = t;
  }

  wgemm_kernel<<<dim3(8, 128), 256, 0, stream>>>(weight, Z, norm2, wbf);
  bvec_kernel<<<2048, 256, 0, stream>>>(wbf, mean, bias, bvec);
  final_gemm_kernel<<<dim3(16, 256), 256, 0, stream>>>(x, wbf, bvec, out);
}